// Round 2
// baseline (144.682 us; speedup 1.0000x reference)
//
#include <hip/hip_runtime.h>
#include <math.h>

// Cosine similarity per matching row: out[r] = dot(a[r,:], b[r,:]) /
// (||a[r,:]|| * ||b[r,:]||), D = 256 floats per row, eps-guarded.
//
// Round-6: force true memory-level parallelism with inline asm.
// Round-5 counter evidence: VGPR_Count=24 -> the compiler serialized the
// "8-deep" C-level load batch into ~2 loads in flight per wave (8 f4 loads
// need >=32 data VGPRs). Effective read BW stuck at ~3 TB/s while neither
// HBM (6.3 TB/s achievable) nor L3 was saturated.
// This version:
//  - one-shot: each wave owns 8 consecutive rows (65536 rows / 8192 waves),
//    issues 16 x global_load_dwordx4 (16 KiB) back-to-back as asm volatile
//    (mutual order guaranteed, compiler cannot re-serialize),
//  - addresses via SGPR base + 32-bit voffset + offset:{0,1024,2048,3072}
//    immediates (2 voffset VGPRs total),
//  - s_waitcnt vmcnt(0) asm + sched_barrier(0) fence (rule: "memory" clobber
//    does not order register-only consumers),
//  - __launch_bounds__(256,4): VGPR cap 128 so 64 data regs fit; 4 waves/SIMD.

#define EPS 1e-12f

typedef float f4 __attribute__((ext_vector_type(4)));

#define GLOAD(dst, voff, sbase, imm)                                  \
    asm volatile("global_load_dwordx4 %0, %1, %2 offset:" #imm        \
                 : "=&v"(dst) : "v"(voff), "s"(sbase) : "memory")

#define ROW_REDUCE_STORE(av, bv, r)                                        \
    do {                                                                   \
        float saa = av.x * av.x + av.y * av.y + av.z * av.z + av.w * av.w; \
        float sbb = bv.x * bv.x + bv.y * bv.y + bv.z * bv.z + bv.w * bv.w; \
        float sab = av.x * bv.x + av.y * bv.y + av.z * bv.z + av.w * bv.w; \
        _Pragma("unroll")                                                  \
        for (int off = 32; off > 0; off >>= 1) {                           \
            saa += __shfl_xor(saa, off, 64);                               \
            sbb += __shfl_xor(sbb, off, 64);                               \
            sab += __shfl_xor(sab, off, 64);                               \
        }                                                                  \
        if (lane == 0) {                                                   \
            const float denom =                                            \
                sqrtf(fmaxf(saa, EPS)) * sqrtf(fmaxf(sbb, EPS));           \
            out[base + r] = sab / denom;                                   \
        }                                                                  \
    } while (0)

__global__ __launch_bounds__(256, 4) void cosine_rows_kernel(
    const float* __restrict__ a,
    const float* __restrict__ b,
    float* __restrict__ out,
    int nrows)
{
    const int lane = threadIdx.x & 63;
    const int wid  = (blockIdx.x << 2) + (threadIdx.x >> 6);
    const int nw   = gridDim.x << 2;

    for (int base = wid * 8; base < nrows; base += nw * 8) {
        // byte offsets: row stride = 256 floats = 1024 B; lane covers 16 B
        const unsigned voff0 = (unsigned)base * 1024u + (unsigned)lane * 16u;
        const unsigned voff1 = voff0 + 4096u;  // rows base+4..base+7

        f4 av0, av1, av2, av3, av4, av5, av6, av7;
        f4 bv0, bv1, bv2, bv3, bv4, bv5, bv6, bv7;

        // 16 x 1 KiB wave-loads, issued back-to-back: 16 KiB in flight.
        GLOAD(av0, voff0, a, 0);
        GLOAD(av1, voff0, a, 1024);
        GLOAD(av2, voff0, a, 2048);
        GLOAD(av3, voff0, a, 3072);
        GLOAD(av4, voff1, a, 0);
        GLOAD(av5, voff1, a, 1024);
        GLOAD(av6, voff1, a, 2048);
        GLOAD(av7, voff1, a, 3072);
        GLOAD(bv0, voff0, b, 0);
        GLOAD(bv1, voff0, b, 1024);
        GLOAD(bv2, voff0, b, 2048);
        GLOAD(bv3, voff0, b, 3072);
        GLOAD(bv4, voff1, b, 0);
        GLOAD(bv5, voff1, b, 1024);
        GLOAD(bv6, voff1, b, 2048);
        GLOAD(bv7, voff1, b, 3072);

        asm volatile("s_waitcnt vmcnt(0)" ::: "memory");
        __builtin_amdgcn_sched_barrier(0);

        ROW_REDUCE_STORE(av0, bv0, 0);
        ROW_REDUCE_STORE(av1, bv1, 1);
        ROW_REDUCE_STORE(av2, bv2, 2);
        ROW_REDUCE_STORE(av3, bv3, 3);
        ROW_REDUCE_STORE(av4, bv4, 4);
        ROW_REDUCE_STORE(av5, bv5, 5);
        ROW_REDUCE_STORE(av6, bv6, 6);
        ROW_REDUCE_STORE(av7, bv7, 7);
    }
}

extern "C" void kernel_launch(void* const* d_in, const int* in_sizes, int n_in,
                              void* d_out, int out_size, void* d_ws, size_t ws_size,
                              hipStream_t stream) {
    const float* a = (const float*)d_in[0];
    const float* b = (const float*)d_in[1];
    float* out = (float*)d_out;

    const int nrows = out_size;   // 16 * 4096 = 65536 (divisible by 8)
    const int blocks = 2048;      // 8192 waves x 8 rows = 65536: one shot

    cosine_rows_kernel<<<blocks, 256, 0, stream>>>(a, b, out, nrows);
}